// Round 1
// baseline (4049.295 us; speedup 1.0000x reference)
//
#include <hip/hip_runtime.h>
#include <math.h>

#define NN 100000
#define NE 1600000

// ---------------- pack weights: Wcat1 = [Wl1 | Wr1] (128x256), Wcat2 = [Wl2 | Wr2 | 0] (128x128)
__global__ void pack_weights(const float* __restrict__ Wl1, const float* __restrict__ Wr1,
                             const float* __restrict__ Wl2, const float* __restrict__ Wr2,
                             float* __restrict__ Wcat1, float* __restrict__ Wcat2) {
    int gid = blockIdx.x * blockDim.x + threadIdx.x;
    if (gid < 128 * 256) {
        int k = gid >> 8, n = gid & 255;
        Wcat1[gid] = (n < 128) ? Wl1[k * 128 + n] : Wr1[k * 128 + (n - 128)];
    } else {
        int g = gid - 128 * 256;
        if (g < 128 * 128) {
            int k = g >> 7, n = g & 127;
            float v = 0.0f;
            if (n < 40)      v = Wl2[k * 40 + n];
            else if (n < 80) v = Wr2[k * 40 + (n - 40)];
            Wcat2[g] = v;
        }
    }
}

// ---------------- degree histogram
__global__ void deg_kernel(const int* __restrict__ ei, float* __restrict__ deg) {
    int e = blockIdx.x * blockDim.x + threadIdx.x;
    if (e < NE) atomicAdd(&deg[ei[NE + e]], 1.0f);
}

// ---------------- fp32 GEMM: C[M,N] = A[M,128] @ W[128,N], N multiple of 64
// 64x64 block tile, 4x4 per-thread micro-tile, K chunked by 32.
__global__ __launch_bounds__(256) void gemm128(const float* __restrict__ A,
                                               const float* __restrict__ W,
                                               float* __restrict__ C, int M, int N) {
    __shared__ float As[32][68];   // [k][m] (transposed), pad 68 to break conflicts
    __shared__ float Ws[32][68];   // [k][n]
    const int K = 128;
    int tid = threadIdx.x;
    int tx = tid & 15, ty = tid >> 4;
    int rowBase = blockIdx.x * 64;
    int colBase = blockIdx.y * 64;
    float acc[4][4] = {{0.f}};

    for (int kc = 0; kc < K; kc += 32) {
        // load A tile: 64 rows x 32 k, transposed into As[k][m]
        {
            int r = tid >> 3, f4 = tid & 7;
#pragma unroll
            for (int rr = 0; rr < 2; ++rr) {
                int m = r + rr * 32;
                int row = rowBase + m;
                float4 a = make_float4(0.f, 0.f, 0.f, 0.f);
                if (row < M) a = *(const float4*)(A + (size_t)row * K + kc + f4 * 4);
                As[f4 * 4 + 0][m] = a.x;
                As[f4 * 4 + 1][m] = a.y;
                As[f4 * 4 + 2][m] = a.z;
                As[f4 * 4 + 3][m] = a.w;
            }
        }
        // load W tile: 32 k x 64 cols
        {
            int kr = tid >> 4, c4 = tid & 15;
#pragma unroll
            for (int rr = 0; rr < 2; ++rr) {
                int k = kr + rr * 16;
                *(float4*)&Ws[k][c4 * 4] =
                    *(const float4*)(W + (size_t)(kc + k) * N + colBase + c4 * 4);
            }
        }
        __syncthreads();
#pragma unroll
        for (int k = 0; k < 32; ++k) {
            float4 a = *(const float4*)&As[k][ty * 4];
            float4 b = *(const float4*)&Ws[k][tx * 4];
            float av[4] = {a.x, a.y, a.z, a.w};
            float bv[4] = {b.x, b.y, b.z, b.w};
#pragma unroll
            for (int i = 0; i < 4; ++i)
#pragma unroll
                for (int j = 0; j < 4; ++j) acc[i][j] += av[i] * bv[j];
        }
        __syncthreads();
    }
#pragma unroll
    for (int i = 0; i < 4; ++i) {
        int row = rowBase + ty * 4 + i;
        if (row < M) {
            float4 o = make_float4(acc[i][0], acc[i][1], acc[i][2], acc[i][3]);
            *(float4*)(C + (size_t)row * N + colBase + tx * 4) = o;
        }
    }
}

// ---------------- scatter layer 1: s1[dst, 0:128] += C1[src, 0:128]  (C1 row stride 256)
__global__ void scatter1(const int* __restrict__ ei, const float* __restrict__ C1,
                         float* __restrict__ s1) {
    int gid = blockIdx.x * 256 + threadIdx.x;
    int e = gid >> 5;
    if (e >= NE) return;
    int q = gid & 31;
    int src = ei[e], dst = ei[NE + e];
    float4 v = *(const float4*)(C1 + (size_t)src * 256 + q * 4);
    float* d = s1 + (size_t)dst * 128 + q * 4;
    atomicAdd(d + 0, v.x);
    atomicAdd(d + 1, v.y);
    atomicAdd(d + 2, v.z);
    atomicAdd(d + 3, v.w);
}

// ---------------- h = relu(s1/deg + b1 + C1[:,128:256]), in place over s1
__global__ void combine1(float* __restrict__ s1, const float* __restrict__ C1,
                         const float* __restrict__ deg, const float* __restrict__ b1) {
    int gid = blockIdx.x * 256 + threadIdx.x;
    if (gid >= NN * 32) return;
    int node = gid >> 5, q = gid & 31;
    float inv = 1.0f / fmaxf(deg[node], 1.0f);
    float4 s = *(const float4*)(s1 + (size_t)node * 128 + q * 4);
    float4 r = *(const float4*)(C1 + (size_t)node * 256 + 128 + q * 4);
    float4 bb = *(const float4*)(b1 + q * 4);
    float4 h;
    h.x = fmaxf(s.x * inv + bb.x + r.x, 0.f);
    h.y = fmaxf(s.y * inv + bb.y + r.y, 0.f);
    h.z = fmaxf(s.z * inv + bb.z + r.z, 0.f);
    h.w = fmaxf(s.w * inv + bb.w + r.w, 0.f);
    *(float4*)(s1 + (size_t)node * 128 + q * 4) = h;
}

// ---------------- scatter layer 2: s2[dst, 0:40] += C2[src, 0:40]  (C2 row stride 128)
__global__ void scatter2(const int* __restrict__ ei, const float* __restrict__ C2,
                         float* __restrict__ s2) {
    int gid = blockIdx.x * 256 + threadIdx.x;
    int e = gid / 10;
    if (e >= NE) return;
    int q = gid % 10;
    int src = ei[e], dst = ei[NE + e];
    float4 v = *(const float4*)(C2 + (size_t)src * 128 + q * 4);
    float* d = s2 + (size_t)dst * 40 + q * 4;
    atomicAdd(d + 0, v.x);
    atomicAdd(d + 1, v.y);
    atomicAdd(d + 2, v.z);
    atomicAdd(d + 3, v.w);
}

// ---------------- out = log_softmax(s2/deg + b2 + C2[:,40:80])
__global__ void final_kernel(const float* __restrict__ s2, const float* __restrict__ C2,
                             const float* __restrict__ deg, const float* __restrict__ b2,
                             float* __restrict__ out) {
    int n = blockIdx.x * 256 + threadIdx.x;
    if (n >= NN) return;
    float inv = 1.0f / fmaxf(deg[n], 1.0f);
    float v[40];
#pragma unroll
    for (int q = 0; q < 10; ++q) {
        float4 s = *(const float4*)(s2 + (size_t)n * 40 + q * 4);
        float4 z = *(const float4*)(C2 + (size_t)n * 128 + 40 + q * 4);
        float4 bb = *(const float4*)(b2 + q * 4);
        v[q * 4 + 0] = s.x * inv + bb.x + z.x;
        v[q * 4 + 1] = s.y * inv + bb.y + z.y;
        v[q * 4 + 2] = s.z * inv + bb.z + z.z;
        v[q * 4 + 3] = s.w * inv + bb.w + z.w;
    }
    float m = v[0];
#pragma unroll
    for (int i = 1; i < 40; ++i) m = fmaxf(m, v[i]);
    float sum = 0.f;
#pragma unroll
    for (int i = 0; i < 40; ++i) sum += expf(v[i] - m);
    float lse = m + logf(sum);
#pragma unroll
    for (int q = 0; q < 10; ++q) {
        float4 o = make_float4(v[q * 4 + 0] - lse, v[q * 4 + 1] - lse,
                               v[q * 4 + 2] - lse, v[q * 4 + 3] - lse);
        *(float4*)(out + (size_t)n * 40 + q * 4) = o;
    }
}

extern "C" void kernel_launch(void* const* d_in, const int* in_sizes, int n_in,
                              void* d_out, int out_size, void* d_ws, size_t ws_size,
                              hipStream_t stream) {
    const float* x   = (const float*)d_in[0];
    const int*   ei  = (const int*)d_in[1];
    const float* Wl1 = (const float*)d_in[2];
    const float* b1  = (const float*)d_in[3];
    const float* Wr1 = (const float*)d_in[4];
    const float* Wl2 = (const float*)d_in[5];
    const float* b2  = (const float*)d_in[6];
    const float* Wr2 = (const float*)d_in[7];
    float* out = (float*)d_out;

    char* ws = (char*)d_ws;
    size_t off = 0;
    auto alloc = [&](size_t bytes) -> void* {
        void* p = ws + off;
        off = (off + bytes + 255) & ~(size_t)255;
        return p;
    };
    float* deg   = (float*)alloc((size_t)NN * 4);
    float* Wcat1 = (float*)alloc((size_t)128 * 256 * 4);
    float* Wcat2 = (float*)alloc((size_t)128 * 128 * 4);
    float* C1    = (float*)alloc((size_t)NN * 256 * 4);  // reused as C2
    float* s1    = (float*)alloc((size_t)NN * 128 * 4);  // reused as h (in place)
    float* s2    = (float*)alloc((size_t)NN * 40 * 4);
    float* C2    = C1;

    hipMemsetAsync(deg, 0, (size_t)NN * 4, stream);
    hipMemsetAsync(s1, 0, (size_t)NN * 128 * 4, stream);
    hipMemsetAsync(s2, 0, (size_t)NN * 40 * 4, stream);

    pack_weights<<<(128 * 256 + 128 * 128 + 255) / 256, 256, 0, stream>>>(Wl1, Wr1, Wl2, Wr2,
                                                                          Wcat1, Wcat2);
    deg_kernel<<<(NE + 255) / 256, 256, 0, stream>>>(ei, deg);

    dim3 g1((NN + 63) / 64, 4);
    gemm128<<<g1, 256, 0, stream>>>(x, Wcat1, C1, NN, 256);

    scatter1<<<(NE * 32 + 255) / 256, 256, 0, stream>>>(ei, C1, s1);
    combine1<<<(NN * 32 + 255) / 256, 256, 0, stream>>>(s1, C1, deg, b1);

    dim3 g2((NN + 63) / 64, 2);
    gemm128<<<g2, 256, 0, stream>>>(s1, Wcat2, C2, NN, 128);

    scatter2<<<(NE * 10 + 255) / 256, 256, 0, stream>>>(ei, C2, s2);
    final_kernel<<<(NN + 255) / 256, 256, 0, stream>>>(s2, C2, deg, b2, out);
}

// Round 2
// 876.122 us; speedup vs baseline: 4.6218x; 4.6218x over previous
//
#include <hip/hip_runtime.h>
#include <math.h>

#define NN 100000
#define NE 1600000

// ---------------- pack weights: Wcat1 = [Wl1 | Wr1] (128x256), Wcat2 = [Wl2 | Wr2 | 0] (128x128)
__global__ void pack_weights(const float* __restrict__ Wl1, const float* __restrict__ Wr1,
                             const float* __restrict__ Wl2, const float* __restrict__ Wr2,
                             float* __restrict__ Wcat1, float* __restrict__ Wcat2) {
    int gid = blockIdx.x * blockDim.x + threadIdx.x;
    if (gid < 128 * 256) {
        int k = gid >> 8, n = gid & 255;
        Wcat1[gid] = (n < 128) ? Wl1[k * 128 + n] : Wr1[k * 128 + (n - 128)];
    } else {
        int g = gid - 128 * 256;
        if (g < 128 * 128) {
            int k = g >> 7, n = g & 127;
            float v = 0.0f;
            if (n < 40)      v = Wl2[k * 40 + n];
            else if (n < 80) v = Wr2[k * 40 + (n - 40)];
            Wcat2[g] = v;
        }
    }
}

// ---------------- int degree histogram over dst
__global__ void deg_hist(const int* __restrict__ ei, int* __restrict__ degi) {
    int e = blockIdx.x * blockDim.x + threadIdx.x;
    if (e < NE) atomicAdd(&degi[ei[NE + e]], 1);
}

// ---------------- single-block exclusive scan: offsets[0..NN], cursor init
__global__ __launch_bounds__(256) void scan_kernel(const int* __restrict__ degi,
                                                   int* __restrict__ offsets,
                                                   int* __restrict__ cursor) {
    __shared__ int part[256];
    int t = threadIdx.x;
    const int chunk = (NN + 255) / 256;  // 391
    int lo = t * chunk, hi = min(lo + chunk, NN);
    int s = 0;
    for (int i = lo; i < hi; ++i) s += degi[i];
    part[t] = s;
    __syncthreads();
    // inclusive Hillis-Steele scan in LDS
    for (int d = 1; d < 256; d <<= 1) {
        int tmp = (t >= d) ? part[t - d] : 0;
        __syncthreads();
        part[t] += tmp;
        __syncthreads();
    }
    int running = part[t] - s;  // exclusive prefix
    for (int i = lo; i < hi; ++i) {
        offsets[i] = running;
        cursor[i] = running;
        running += degi[i];
    }
    if (t == 255) offsets[NN] = running;  // == NE
}

// ---------------- counting-sort fill: sorted_src grouped by dst
__global__ void fill_kernel(const int* __restrict__ ei, int* __restrict__ cursor,
                            int* __restrict__ sorted_src) {
    int e = blockIdx.x * blockDim.x + threadIdx.x;
    if (e >= NE) return;
    int dst = ei[NE + e];
    int pos = atomicAdd(&cursor[dst], 1);
    sorted_src[pos] = ei[e];
}

// ---------------- fp32 GEMM: C[M,N] = A[M,128] @ W[128,N], N multiple of 64
__global__ __launch_bounds__(256) void gemm128(const float* __restrict__ A,
                                               const float* __restrict__ W,
                                               float* __restrict__ C, int M, int N) {
    __shared__ float As[32][68];
    __shared__ float Ws[32][68];
    const int K = 128;
    int tid = threadIdx.x;
    int tx = tid & 15, ty = tid >> 4;
    int rowBase = blockIdx.x * 64;
    int colBase = blockIdx.y * 64;
    float acc[4][4] = {{0.f}};

    for (int kc = 0; kc < K; kc += 32) {
        {
            int r = tid >> 3, f4 = tid & 7;
#pragma unroll
            for (int rr = 0; rr < 2; ++rr) {
                int m = r + rr * 32;
                int row = rowBase + m;
                float4 a = make_float4(0.f, 0.f, 0.f, 0.f);
                if (row < M) a = *(const float4*)(A + (size_t)row * K + kc + f4 * 4);
                As[f4 * 4 + 0][m] = a.x;
                As[f4 * 4 + 1][m] = a.y;
                As[f4 * 4 + 2][m] = a.z;
                As[f4 * 4 + 3][m] = a.w;
            }
        }
        {
            int kr = tid >> 4, c4 = tid & 15;
#pragma unroll
            for (int rr = 0; rr < 2; ++rr) {
                int k = kr + rr * 16;
                *(float4*)&Ws[k][c4 * 4] =
                    *(const float4*)(W + (size_t)(kc + k) * N + colBase + c4 * 4);
            }
        }
        __syncthreads();
#pragma unroll
        for (int k = 0; k < 32; ++k) {
            float4 a = *(const float4*)&As[k][ty * 4];
            float4 b = *(const float4*)&Ws[k][tx * 4];
            float av[4] = {a.x, a.y, a.z, a.w};
            float bv[4] = {b.x, b.y, b.z, b.w};
#pragma unroll
            for (int i = 0; i < 4; ++i)
#pragma unroll
                for (int j = 0; j < 4; ++j) acc[i][j] += av[i] * bv[j];
        }
        __syncthreads();
    }
#pragma unroll
    for (int i = 0; i < 4; ++i) {
        int row = rowBase + ty * 4 + i;
        if (row < M) {
            float4 o = make_float4(acc[i][0], acc[i][1], acc[i][2], acc[i][3]);
            *(float4*)(C + (size_t)row * N + colBase + tx * 4) = o;
        }
    }
}

// ---------------- aggregate layer 1 (fused combine): one wave per node
// lane l owns channels [2l, 2l+1]. h = relu(mean_gather(C1[:,0:128]) + b1 + C1[node,128:256])
__global__ __launch_bounds__(256) void aggregate1(const int* __restrict__ offsets,
                                                  const int* __restrict__ sorted_src,
                                                  const float* __restrict__ C1,
                                                  const float* __restrict__ b1,
                                                  float* __restrict__ s1) {
    int w = (blockIdx.x * blockDim.x + threadIdx.x) >> 6;
    int lane = threadIdx.x & 63;
    if (w >= NN) return;
    int start = offsets[w], end = offsets[w + 1];
    float2 acc0 = make_float2(0.f, 0.f), acc1 = make_float2(0.f, 0.f);
    int i = start;
    for (; i + 1 < end; i += 2) {
        int s0 = sorted_src[i], s1v = sorted_src[i + 1];
        float2 v0 = *(const float2*)(C1 + (size_t)s0 * 256 + lane * 2);
        float2 v1 = *(const float2*)(C1 + (size_t)s1v * 256 + lane * 2);
        acc0.x += v0.x; acc0.y += v0.y;
        acc1.x += v1.x; acc1.y += v1.y;
    }
    if (i < end) {
        int s0 = sorted_src[i];
        float2 v0 = *(const float2*)(C1 + (size_t)s0 * 256 + lane * 2);
        acc0.x += v0.x; acc0.y += v0.y;
    }
    float inv = 1.0f / fmaxf((float)(end - start), 1.0f);
    float2 r = *(const float2*)(C1 + (size_t)w * 256 + 128 + lane * 2);
    float2 bb = *(const float2*)(b1 + lane * 2);
    float2 h;
    h.x = fmaxf((acc0.x + acc1.x) * inv + bb.x + r.x, 0.f);
    h.y = fmaxf((acc0.y + acc1.y) * inv + bb.y + r.y, 0.f);
    *(float2*)(s1 + (size_t)w * 128 + lane * 2) = h;
}

// ---------------- aggregate layer 2 + log_softmax: one wave per node, lanes 0..39 own 1 ch
__global__ __launch_bounds__(256) void aggregate2(const int* __restrict__ offsets,
                                                  const int* __restrict__ sorted_src,
                                                  const float* __restrict__ C2,
                                                  const float* __restrict__ b2,
                                                  float* __restrict__ out) {
    int w = (blockIdx.x * blockDim.x + threadIdx.x) >> 6;
    int lane = threadIdx.x & 63;
    if (w >= NN) return;
    int start = offsets[w], end = offsets[w + 1];
    float acc = 0.f;
    int i = start;
    for (; i + 1 < end; i += 2) {
        int s0 = sorted_src[i], s1v = sorted_src[i + 1];
        if (lane < 40) {
            acc += C2[(size_t)s0 * 128 + lane];
            acc += C2[(size_t)s1v * 128 + lane];
        }
    }
    if (i < end) {
        int s0 = sorted_src[i];
        if (lane < 40) acc += C2[(size_t)s0 * 128 + lane];
    }
    float inv = 1.0f / fmaxf((float)(end - start), 1.0f);
    float v = -INFINITY;
    if (lane < 40) v = acc * inv + b2[lane] + C2[(size_t)w * 128 + 40 + lane];
    // wave max
    float m = v;
#pragma unroll
    for (int d = 32; d >= 1; d >>= 1) m = fmaxf(m, __shfl_xor(m, d, 64));
    float e = (lane < 40) ? expf(v - m) : 0.f;
#pragma unroll
    for (int d = 32; d >= 1; d >>= 1) e += __shfl_xor(e, d, 64);
    float lse = m + logf(e);
    if (lane < 40) out[(size_t)w * 40 + lane] = v - lse;
}

extern "C" void kernel_launch(void* const* d_in, const int* in_sizes, int n_in,
                              void* d_out, int out_size, void* d_ws, size_t ws_size,
                              hipStream_t stream) {
    const float* x   = (const float*)d_in[0];
    const int*   ei  = (const int*)d_in[1];
    const float* Wl1 = (const float*)d_in[2];
    const float* b1  = (const float*)d_in[3];
    const float* Wr1 = (const float*)d_in[4];
    const float* Wl2 = (const float*)d_in[5];
    const float* b2  = (const float*)d_in[6];
    const float* Wr2 = (const float*)d_in[7];
    float* out = (float*)d_out;

    char* ws = (char*)d_ws;
    size_t off = 0;
    auto alloc = [&](size_t bytes) -> void* {
        void* p = ws + off;
        off = (off + bytes + 255) & ~(size_t)255;
        return p;
    };
    int*   degi    = (int*)alloc((size_t)NN * 4);
    int*   offsets = (int*)alloc((size_t)(NN + 1) * 4);
    int*   cursor  = (int*)alloc((size_t)NN * 4);
    int*   ssrc    = (int*)alloc((size_t)NE * 4);
    float* Wcat1   = (float*)alloc((size_t)128 * 256 * 4);
    float* Wcat2   = (float*)alloc((size_t)128 * 128 * 4);
    float* C1      = (float*)alloc((size_t)NN * 256 * 4);  // reused as C2
    float* s1      = (float*)alloc((size_t)NN * 128 * 4);  // h
    float* C2      = C1;

    hipMemsetAsync(degi, 0, (size_t)NN * 4, stream);

    pack_weights<<<(128 * 256 + 128 * 128 + 255) / 256, 256, 0, stream>>>(Wl1, Wr1, Wl2, Wr2,
                                                                          Wcat1, Wcat2);
    deg_hist<<<(NE + 255) / 256, 256, 0, stream>>>(ei, degi);
    scan_kernel<<<1, 256, 0, stream>>>(degi, offsets, cursor);
    fill_kernel<<<(NE + 255) / 256, 256, 0, stream>>>(ei, cursor, ssrc);

    dim3 g1((NN + 63) / 64, 4);
    gemm128<<<g1, 256, 0, stream>>>(x, Wcat1, C1, NN, 256);

    aggregate1<<<(NN * 64 + 255) / 256, 256, 0, stream>>>(offsets, ssrc, C1, b1, s1);

    dim3 g2((NN + 63) / 64, 2);
    gemm128<<<g2, 256, 0, stream>>>(s1, Wcat2, C2, NN, 128);

    aggregate2<<<(NN * 64 + 255) / 256, 256, 0, stream>>>(offsets, ssrc, C2, b2, out);
}

// Round 3
// 659.282 us; speedup vs baseline: 6.1420x; 1.3289x over previous
//
#include <hip/hip_runtime.h>
#include <math.h>

#define NN 100000
#define NE 1600000
#define SCAN_CHUNK 512
#define NBLK_SCAN ((NN + SCAN_CHUNK - 1) / SCAN_CHUNK)  // 196

// ---------------- pack weights: Wcat1 = [Wl1 | Wr1] (128x256), Wcat2 = [Wl2 | Wr2 | 0] (128x128)
__global__ void pack_weights(const float* __restrict__ Wl1, const float* __restrict__ Wr1,
                             const float* __restrict__ Wl2, const float* __restrict__ Wr2,
                             float* __restrict__ Wcat1, float* __restrict__ Wcat2) {
    int gid = blockIdx.x * blockDim.x + threadIdx.x;
    if (gid < 128 * 256) {
        int k = gid >> 8, n = gid & 255;
        Wcat1[gid] = (n < 128) ? Wl1[k * 128 + n] : Wr1[k * 128 + (n - 128)];
    } else {
        int g = gid - 128 * 256;
        if (g < 128 * 128) {
            int k = g >> 7, n = g & 127;
            float v = 0.0f;
            if (n < 40)      v = Wl2[k * 40 + n];
            else if (n < 80) v = Wr2[k * 40 + (n - 40)];
            Wcat2[g] = v;
        }
    }
}

// ---------------- int degree histogram over dst
__global__ void deg_hist(const int* __restrict__ ei, int* __restrict__ degi) {
    int e = blockIdx.x * blockDim.x + threadIdx.x;
    if (e < NE) atomicAdd(&degi[ei[NE + e]], 1);
}

// ---------------- scan phase 1: per-block chunk sums
__global__ __launch_bounds__(256) void scan_partials(const int* __restrict__ degi,
                                                     int* __restrict__ partials) {
    __shared__ int lds[4];
    int b = blockIdx.x, t = threadIdx.x;
    int i0 = b * SCAN_CHUNK + t * 2;
    int s = 0;
    if (i0 < NN) s += degi[i0];
    if (i0 + 1 < NN) s += degi[i0 + 1];
#pragma unroll
    for (int d = 32; d >= 1; d >>= 1) s += __shfl_xor(s, d, 64);
    if ((t & 63) == 0) lds[t >> 6] = s;
    __syncthreads();
    if (t == 0) partials[b] = lds[0] + lds[1] + lds[2] + lds[3];
}

// ---------------- scan phase 2: single block scans the partials (NBLK_SCAN <= 256)
__global__ __launch_bounds__(256) void scan_level2(int* __restrict__ partials,
                                                   int* __restrict__ offsets) {
    __shared__ int part[256];
    int t = threadIdx.x;
    int v = (t < NBLK_SCAN) ? partials[t] : 0;
    part[t] = v;
    __syncthreads();
    for (int d = 1; d < 256; d <<= 1) {
        int tmp = (t >= d) ? part[t - d] : 0;
        __syncthreads();
        part[t] += tmp;
        __syncthreads();
    }
    if (t < NBLK_SCAN) partials[t] = part[t] - v;  // exclusive base per block
    if (t == 255) offsets[NN] = part[255];         // total == NE
}

// ---------------- scan phase 3: block-local exclusive scan + base, write offsets & cursor
__global__ __launch_bounds__(256) void scan_finalize(const int* __restrict__ degi,
                                                     const int* __restrict__ partials,
                                                     int* __restrict__ offsets,
                                                     int* __restrict__ cursor) {
    __shared__ int part[256];
    int b = blockIdx.x, t = threadIdx.x;
    int i0 = b * SCAN_CHUNK + t * 2;
    int d0 = (i0 < NN) ? degi[i0] : 0;
    int d1 = (i0 + 1 < NN) ? degi[i0 + 1] : 0;
    int ps = d0 + d1;
    part[t] = ps;
    __syncthreads();
    for (int d = 1; d < 256; d <<= 1) {
        int tmp = (t >= d) ? part[t - d] : 0;
        __syncthreads();
        part[t] += tmp;
        __syncthreads();
    }
    int excl = part[t] - ps + partials[b];
    if (i0 < NN)     { offsets[i0] = excl;          cursor[i0] = excl; }
    if (i0 + 1 < NN) { offsets[i0 + 1] = excl + d0; cursor[i0 + 1] = excl + d0; }
}

// ---------------- counting-sort fill: sorted_src grouped by dst
__global__ void fill_kernel(const int* __restrict__ ei, int* __restrict__ cursor,
                            int* __restrict__ sorted_src) {
    int e = blockIdx.x * blockDim.x + threadIdx.x;
    if (e >= NE) return;
    int dst = ei[NE + e];
    int pos = atomicAdd(&cursor[dst], 1);
    sorted_src[pos] = ei[e];
}

// ---------------- fp32 GEMM: C[M,N] = A[M,128] @ W[128,N], N multiple of 64
__global__ __launch_bounds__(256) void gemm128(const float* __restrict__ A,
                                               const float* __restrict__ W,
                                               float* __restrict__ C, int M, int N) {
    __shared__ float As[32][68];
    __shared__ float Ws[32][68];
    const int K = 128;
    int tid = threadIdx.x;
    int tx = tid & 15, ty = tid >> 4;
    int rowBase = blockIdx.x * 64;
    int colBase = blockIdx.y * 64;
    float acc[4][4] = {{0.f}};

    for (int kc = 0; kc < K; kc += 32) {
        {
            int r = tid >> 3, f4 = tid & 7;
#pragma unroll
            for (int rr = 0; rr < 2; ++rr) {
                int m = r + rr * 32;
                int row = rowBase + m;
                float4 a = make_float4(0.f, 0.f, 0.f, 0.f);
                if (row < M) a = *(const float4*)(A + (size_t)row * K + kc + f4 * 4);
                As[f4 * 4 + 0][m] = a.x;
                As[f4 * 4 + 1][m] = a.y;
                As[f4 * 4 + 2][m] = a.z;
                As[f4 * 4 + 3][m] = a.w;
            }
        }
        {
            int kr = tid >> 4, c4 = tid & 15;
#pragma unroll
            for (int rr = 0; rr < 2; ++rr) {
                int k = kr + rr * 16;
                *(float4*)&Ws[k][c4 * 4] =
                    *(const float4*)(W + (size_t)(kc + k) * N + colBase + c4 * 4);
            }
        }
        __syncthreads();
#pragma unroll
        for (int k = 0; k < 32; ++k) {
            float4 a = *(const float4*)&As[k][ty * 4];
            float4 b = *(const float4*)&Ws[k][tx * 4];
            float av[4] = {a.x, a.y, a.z, a.w};
            float bv[4] = {b.x, b.y, b.z, b.w};
#pragma unroll
            for (int i = 0; i < 4; ++i)
#pragma unroll
                for (int j = 0; j < 4; ++j) acc[i][j] += av[i] * bv[j];
        }
        __syncthreads();
    }
#pragma unroll
    for (int i = 0; i < 4; ++i) {
        int row = rowBase + ty * 4 + i;
        if (row < M) {
            float4 o = make_float4(acc[i][0], acc[i][1], acc[i][2], acc[i][3]);
            *(float4*)(C + (size_t)row * N + colBase + tx * 4) = o;
        }
    }
}

// ---------------- aggregate layer 1 (fused combine): one wave per node
// lane l owns channels [2l, 2l+1]. h = relu(mean_gather(C1[:,0:128]) + b1 + C1[node,128:256])
__global__ __launch_bounds__(256) void aggregate1(const int* __restrict__ offsets,
                                                  const int* __restrict__ sorted_src,
                                                  const float* __restrict__ C1,
                                                  const float* __restrict__ b1,
                                                  float* __restrict__ s1) {
    int w = (blockIdx.x * blockDim.x + threadIdx.x) >> 6;
    int lane = threadIdx.x & 63;
    if (w >= NN) return;
    int start = offsets[w], end = offsets[w + 1];
    float2 acc0 = make_float2(0.f, 0.f), acc1 = make_float2(0.f, 0.f);
    int i = start;
    for (; i + 1 < end; i += 2) {
        int s0 = sorted_src[i], s1v = sorted_src[i + 1];
        float2 v0 = *(const float2*)(C1 + (size_t)s0 * 256 + lane * 2);
        float2 v1 = *(const float2*)(C1 + (size_t)s1v * 256 + lane * 2);
        acc0.x += v0.x; acc0.y += v0.y;
        acc1.x += v1.x; acc1.y += v1.y;
    }
    if (i < end) {
        int s0 = sorted_src[i];
        float2 v0 = *(const float2*)(C1 + (size_t)s0 * 256 + lane * 2);
        acc0.x += v0.x; acc0.y += v0.y;
    }
    float inv = 1.0f / fmaxf((float)(end - start), 1.0f);
    float2 r = *(const float2*)(C1 + (size_t)w * 256 + 128 + lane * 2);
    float2 bb = *(const float2*)(b1 + lane * 2);
    float2 h;
    h.x = fmaxf((acc0.x + acc1.x) * inv + bb.x + r.x, 0.f);
    h.y = fmaxf((acc0.y + acc1.y) * inv + bb.y + r.y, 0.f);
    *(float2*)(s1 + (size_t)w * 128 + lane * 2) = h;
}

// ---------------- aggregate layer 2 + log_softmax: one wave per node, lanes 0..39 own 1 ch
__global__ __launch_bounds__(256) void aggregate2(const int* __restrict__ offsets,
                                                  const int* __restrict__ sorted_src,
                                                  const float* __restrict__ C2,
                                                  const float* __restrict__ b2,
                                                  float* __restrict__ out) {
    int w = (blockIdx.x * blockDim.x + threadIdx.x) >> 6;
    int lane = threadIdx.x & 63;
    if (w >= NN) return;
    int start = offsets[w], end = offsets[w + 1];
    float acc = 0.f;
    int i = start;
    for (; i + 1 < end; i += 2) {
        int s0 = sorted_src[i], s1v = sorted_src[i + 1];
        if (lane < 40) {
            acc += C2[(size_t)s0 * 128 + lane];
            acc += C2[(size_t)s1v * 128 + lane];
        }
    }
    if (i < end) {
        int s0 = sorted_src[i];
        if (lane < 40) acc += C2[(size_t)s0 * 128 + lane];
    }
    float inv = 1.0f / fmaxf((float)(end - start), 1.0f);
    float v = -INFINITY;
    if (lane < 40) v = acc * inv + b2[lane] + C2[(size_t)w * 128 + 40 + lane];
    float m = v;
#pragma unroll
    for (int d = 32; d >= 1; d >>= 1) m = fmaxf(m, __shfl_xor(m, d, 64));
    float e = (lane < 40) ? expf(v - m) : 0.f;
#pragma unroll
    for (int d = 32; d >= 1; d >>= 1) e += __shfl_xor(e, d, 64);
    float lse = m + logf(e);
    if (lane < 40) out[(size_t)w * 40 + lane] = v - lse;
}

extern "C" void kernel_launch(void* const* d_in, const int* in_sizes, int n_in,
                              void* d_out, int out_size, void* d_ws, size_t ws_size,
                              hipStream_t stream) {
    const float* x   = (const float*)d_in[0];
    const int*   ei  = (const int*)d_in[1];
    const float* Wl1 = (const float*)d_in[2];
    const float* b1  = (const float*)d_in[3];
    const float* Wr1 = (const float*)d_in[4];
    const float* Wl2 = (const float*)d_in[5];
    const float* b2  = (const float*)d_in[6];
    const float* Wr2 = (const float*)d_in[7];
    float* out = (float*)d_out;

    char* ws = (char*)d_ws;
    size_t off = 0;
    auto alloc = [&](size_t bytes) -> void* {
        void* p = ws + off;
        off = (off + bytes + 255) & ~(size_t)255;
        return p;
    };
    int*   degi     = (int*)alloc((size_t)NN * 4);
    int*   offsets  = (int*)alloc((size_t)(NN + 1) * 4);
    int*   cursor   = (int*)alloc((size_t)NN * 4);
    int*   partials = (int*)alloc((size_t)NBLK_SCAN * 4);
    int*   ssrc     = (int*)alloc((size_t)NE * 4);
    float* Wcat1    = (float*)alloc((size_t)128 * 256 * 4);
    float* Wcat2    = (float*)alloc((size_t)128 * 128 * 4);
    float* C1       = (float*)alloc((size_t)NN * 256 * 4);  // reused as C2
    float* s1       = (float*)alloc((size_t)NN * 128 * 4);  // h
    float* C2       = C1;

    hipMemsetAsync(degi, 0, (size_t)NN * 4, stream);

    pack_weights<<<(128 * 256 + 128 * 128 + 255) / 256, 256, 0, stream>>>(Wl1, Wr1, Wl2, Wr2,
                                                                          Wcat1, Wcat2);
    deg_hist<<<(NE + 255) / 256, 256, 0, stream>>>(ei, degi);
    scan_partials<<<NBLK_SCAN, 256, 0, stream>>>(degi, partials);
    scan_level2<<<1, 256, 0, stream>>>(partials, offsets);
    scan_finalize<<<NBLK_SCAN, 256, 0, stream>>>(degi, partials, offsets, cursor);
    fill_kernel<<<(NE + 255) / 256, 256, 0, stream>>>(ei, cursor, ssrc);

    dim3 g1((NN + 63) / 64, 4);
    gemm128<<<g1, 256, 0, stream>>>(x, Wcat1, C1, NN, 256);

    aggregate1<<<(NN * 64 + 255) / 256, 256, 0, stream>>>(offsets, ssrc, C1, b1, s1);

    dim3 g2((NN + 63) / 64, 2);
    gemm128<<<g2, 256, 0, stream>>>(s1, Wcat2, C2, NN, 128);

    aggregate2<<<(NN * 64 + 255) / 256, 256, 0, stream>>>(offsets, ssrc, C2, b2, out);
}

// Round 4
// 551.601 us; speedup vs baseline: 7.3410x; 1.1952x over previous
//
#include <hip/hip_runtime.h>
#include <math.h>

#define NN 100000
#define NE 1600000
#define SCAN_CHUNK 512
#define NBLK_SCAN ((NN + SCAN_CHUNK - 1) / SCAN_CHUNK)  // 196

typedef __attribute__((ext_vector_type(8))) short short8;
typedef __attribute__((ext_vector_type(4))) float f32x4;
typedef unsigned short ushort_t;
typedef unsigned int uint_t;

__device__ inline ushort_t f2bf(float f) {  // RNE
    uint_t u = __builtin_bit_cast(uint_t, f);
    u += 0x7FFFu + ((u >> 16) & 1u);
    return (ushort_t)(u >> 16);
}
__device__ inline float bf2f(ushort_t b) {
    uint_t u = (uint_t)b << 16;
    return __builtin_bit_cast(float, u);
}
__device__ inline float bits2f(uint_t u) { return __builtin_bit_cast(float, u); }

// ---------------- pack weights (bf16, pre-transposed [N][K]):
// W1T = [Wl1 | Wr1]^T  (256 n x 128 k),  W2T = [Wl2 | Wr2 | 0]^T (128 n x 128 k)
__global__ void pack_weights(const float* __restrict__ Wl1, const float* __restrict__ Wr1,
                             const float* __restrict__ Wl2, const float* __restrict__ Wr2,
                             ushort_t* __restrict__ W1T, ushort_t* __restrict__ W2T) {
    int gid = blockIdx.x * blockDim.x + threadIdx.x;
    if (gid < 256 * 128) {
        int n = gid >> 7, k = gid & 127;
        float v = (n < 128) ? Wl1[k * 128 + n] : Wr1[k * 128 + (n - 128)];
        W1T[gid] = f2bf(v);
    } else {
        int g = gid - 256 * 128;
        if (g < 128 * 128) {
            int n = g >> 7, k = g & 127;
            float v = 0.0f;
            if (n < 40)      v = Wl2[k * 40 + n];
            else if (n < 80) v = Wr2[k * 40 + (n - 40)];
            W2T[g] = f2bf(v);
        }
    }
}

// ---------------- cast x -> bf16 (4 elems/thread)
__global__ void cast_x(const float* __restrict__ x, ushort_t* __restrict__ xb) {
    int g = blockIdx.x * 256 + threadIdx.x;
    if (g >= NN * 32) return;
    float4 v = ((const float4*)x)[g];
    ushort4 o;
    o.x = f2bf(v.x); o.y = f2bf(v.y); o.z = f2bf(v.z); o.w = f2bf(v.w);
    ((ushort4*)xb)[g] = o;
}

// ---------------- int degree histogram over dst
__global__ void deg_hist(const int* __restrict__ ei, int* __restrict__ degi) {
    int e = blockIdx.x * blockDim.x + threadIdx.x;
    if (e < NE) atomicAdd(&degi[ei[NE + e]], 1);
}

// ---------------- scan phase 1: per-block chunk sums
__global__ __launch_bounds__(256) void scan_partials(const int* __restrict__ degi,
                                                     int* __restrict__ partials) {
    __shared__ int lds[4];
    int b = blockIdx.x, t = threadIdx.x;
    int i0 = b * SCAN_CHUNK + t * 2;
    int s = 0;
    if (i0 < NN) s += degi[i0];
    if (i0 + 1 < NN) s += degi[i0 + 1];
#pragma unroll
    for (int d = 32; d >= 1; d >>= 1) s += __shfl_xor(s, d, 64);
    if ((t & 63) == 0) lds[t >> 6] = s;
    __syncthreads();
    if (t == 0) partials[b] = lds[0] + lds[1] + lds[2] + lds[3];
}

// ---------------- scan phase 2: single block scans the partials (NBLK_SCAN <= 256)
__global__ __launch_bounds__(256) void scan_level2(int* __restrict__ partials,
                                                   int* __restrict__ offsets) {
    __shared__ int part[256];
    int t = threadIdx.x;
    int v = (t < NBLK_SCAN) ? partials[t] : 0;
    part[t] = v;
    __syncthreads();
    for (int d = 1; d < 256; d <<= 1) {
        int tmp = (t >= d) ? part[t - d] : 0;
        __syncthreads();
        part[t] += tmp;
        __syncthreads();
    }
    if (t < NBLK_SCAN) partials[t] = part[t] - v;
    if (t == 255) offsets[NN] = part[255];
}

// ---------------- scan phase 3: block-local exclusive scan + base
__global__ __launch_bounds__(256) void scan_finalize(const int* __restrict__ degi,
                                                     const int* __restrict__ partials,
                                                     int* __restrict__ offsets,
                                                     int* __restrict__ cursor) {
    __shared__ int part[256];
    int b = blockIdx.x, t = threadIdx.x;
    int i0 = b * SCAN_CHUNK + t * 2;
    int d0 = (i0 < NN) ? degi[i0] : 0;
    int d1 = (i0 + 1 < NN) ? degi[i0 + 1] : 0;
    int ps = d0 + d1;
    part[t] = ps;
    __syncthreads();
    for (int d = 1; d < 256; d <<= 1) {
        int tmp = (t >= d) ? part[t - d] : 0;
        __syncthreads();
        part[t] += tmp;
        __syncthreads();
    }
    int excl = part[t] - ps + partials[b];
    if (i0 < NN)     { offsets[i0] = excl;          cursor[i0] = excl; }
    if (i0 + 1 < NN) { offsets[i0 + 1] = excl + d0; cursor[i0 + 1] = excl + d0; }
}

// ---------------- counting-sort fill
__global__ void fill_kernel(const int* __restrict__ ei, int* __restrict__ cursor,
                            int* __restrict__ sorted_src) {
    int e = blockIdx.x * blockDim.x + threadIdx.x;
    if (e >= NE) return;
    int dst = ei[NE + e];
    int pos = atomicAdd(&cursor[dst], 1);
    sorted_src[pos] = ei[e];
}

// ---------------- bf16 MFMA GEMM: [M,128]bf16 @ Bt^T (Bt is [N][128]bf16)
// Output split: cols [0,split) -> G (bf16, row stride = split),
//               cols [split,rootEnd) -> Croot (fp32, row stride = rootEnd-split)
// Block tile 128x128, 4 waves in 2x2 (each 64x64), full K=128 in two BK=64 chunks.
__global__ __launch_bounds__(256) void gemm_mfma(const ushort_t* __restrict__ A,
                                                 const ushort_t* __restrict__ Bt,
                                                 ushort_t* __restrict__ G,
                                                 float* __restrict__ Croot,
                                                 int M, int split, int rootEnd) {
    __shared__ __align__(16) ushort_t As[128 * 72];  // [m][k], stride 72 (pad) -> 2-way only
    __shared__ __align__(16) ushort_t Bs[128 * 72];  // [n][k]
    int tid = threadIdx.x;
    int lane = tid & 63, wid = tid >> 6;
    int quad = lane >> 4, l15 = lane & 15;
    int wm = (wid & 1) * 64, wn = (wid >> 1) * 64;
    int mBase = blockIdx.x * 128, nBase = blockIdx.y * 128;
    int rootW = rootEnd - split;

    f32x4 acc[4][4];
#pragma unroll
    for (int i = 0; i < 4; ++i)
#pragma unroll
        for (int j = 0; j < 4; ++j) acc[i][j] = (f32x4){0.f, 0.f, 0.f, 0.f};

    int lrow = tid >> 1;            // 0..127
    int lcol = (tid & 1) * 32;      // bf16 offset within 64-wide chunk
    int arow = mBase + lrow;
    const ushort_t* aSrc = A + (size_t)arow * 128 + lcol;
    const ushort_t* bSrc = Bt + (size_t)(nBase + lrow) * 128 + lcol;
    ushort_t* aDst = &As[lrow * 72 + lcol];
    ushort_t* bDst = &Bs[lrow * 72 + lcol];

    for (int kc = 0; kc < 128; kc += 64) {
#pragma unroll
        for (int ii = 0; ii < 4; ++ii) {
            uint4 av = make_uint4(0, 0, 0, 0);
            if (arow < M) av = *(const uint4*)(aSrc + kc + ii * 8);
            *(uint4*)(aDst + ii * 8) = av;
            uint4 bv = *(const uint4*)(bSrc + kc + ii * 8);
            *(uint4*)(bDst + ii * 8) = bv;
        }
        __syncthreads();
#pragma unroll
        for (int kk = 0; kk < 2; ++kk) {
            short8 af[4], bf[4];
#pragma unroll
            for (int i = 0; i < 4; ++i)
                af[i] = *(const short8*)&As[(wm + i * 16 + l15) * 72 + kk * 32 + quad * 8];
#pragma unroll
            for (int j = 0; j < 4; ++j)
                bf[j] = *(const short8*)&Bs[(wn + j * 16 + l15) * 72 + kk * 32 + quad * 8];
#pragma unroll
            for (int i = 0; i < 4; ++i)
#pragma unroll
                for (int j = 0; j < 4; ++j)
                    acc[i][j] = __builtin_amdgcn_mfma_f32_16x16x32_bf16(af[i], bf[j],
                                                                        acc[i][j], 0, 0, 0);
        }
        __syncthreads();
    }
    // epilogue: D layout col=lane&15, row=quad*4+reg
#pragma unroll
    for (int i = 0; i < 4; ++i) {
#pragma unroll
        for (int r = 0; r < 4; ++r) {
            int m = mBase + wm + i * 16 + quad * 4 + r;
            if (m >= M) continue;
#pragma unroll
            for (int j = 0; j < 4; ++j) {
                int n = nBase + wn + j * 16 + l15;
                float v = acc[i][j][r];
                if (n < split) G[(size_t)m * split + n] = f2bf(v);
                else if (n < rootEnd) Croot[(size_t)m * rootW + (n - split)] = v;
            }
        }
    }
}

// ---------------- aggregate layer 1: one wave/node, lane owns ch [2l,2l+1]
// h = relu(mean_gather(G1) + b1 + C1root[node]) -> s1b (bf16)
__global__ __launch_bounds__(256) void aggregate1(const int* __restrict__ offsets,
                                                  const int* __restrict__ ssrc,
                                                  const ushort_t* __restrict__ G1,
                                                  const float* __restrict__ C1root,
                                                  const float* __restrict__ b1,
                                                  ushort_t* __restrict__ s1b) {
    int w = (blockIdx.x * blockDim.x + threadIdx.x) >> 6;
    int lane = threadIdx.x & 63;
    if (w >= NN) return;
    int start = offsets[w], end = offsets[w + 1];
    const uint_t* G = (const uint_t*)G1;
    float a0 = 0.f, a1 = 0.f, c0 = 0.f, c1 = 0.f;
    int i = start;
    for (; i + 1 < end; i += 2) {
        int s0 = ssrc[i], s1v = ssrc[i + 1];
        uint_t u0 = G[(size_t)s0 * 64 + lane];
        uint_t u1 = G[(size_t)s1v * 64 + lane];
        a0 += bits2f(u0 << 16); a1 += bits2f(u0 & 0xFFFF0000u);
        c0 += bits2f(u1 << 16); c1 += bits2f(u1 & 0xFFFF0000u);
    }
    if (i < end) {
        uint_t u0 = G[(size_t)ssrc[i] * 64 + lane];
        a0 += bits2f(u0 << 16); a1 += bits2f(u0 & 0xFFFF0000u);
    }
    float inv = 1.0f / fmaxf((float)(end - start), 1.0f);
    float2 r = *(const float2*)(C1root + (size_t)w * 128 + lane * 2);
    float2 bb = *(const float2*)(b1 + lane * 2);
    float h0 = fmaxf((a0 + c0) * inv + bb.x + r.x, 0.f);
    float h1 = fmaxf((a1 + c1) * inv + bb.y + r.y, 0.f);
    uint_t o = ((uint_t)f2bf(h1) << 16) | (uint_t)f2bf(h0);
    ((uint_t*)s1b)[(size_t)w * 64 + lane] = o;
}

// ---------------- aggregate layer 2 + log_softmax: one wave/node, lanes 0..39
__global__ __launch_bounds__(256) void aggregate2(const int* __restrict__ offsets,
                                                  const int* __restrict__ ssrc,
                                                  const ushort_t* __restrict__ G2,
                                                  const float* __restrict__ C2root,
                                                  const float* __restrict__ b2,
                                                  float* __restrict__ out) {
    int w = (blockIdx.x * blockDim.x + threadIdx.x) >> 6;
    int lane = threadIdx.x & 63;
    if (w >= NN) return;
    int start = offsets[w], end = offsets[w + 1];
    bool act = lane < 40;
    float acc = 0.f;
    int i = start;
    for (; i + 1 < end; i += 2) {
        int s0 = ssrc[i], s1v = ssrc[i + 1];
        if (act) {
            acc += bf2f(G2[(size_t)s0 * 40 + lane]);
            acc += bf2f(G2[(size_t)s1v * 40 + lane]);
        }
    }
    if (i < end && act) acc += bf2f(G2[(size_t)ssrc[i] * 40 + lane]);
    float inv = 1.0f / fmaxf((float)(end - start), 1.0f);
    float v = -INFINITY;
    if (act) v = acc * inv + b2[lane] + C2root[(size_t)w * 40 + lane];
    float m = v;
#pragma unroll
    for (int d = 32; d >= 1; d >>= 1) m = fmaxf(m, __shfl_xor(m, d, 64));
    float e = act ? expf(v - m) : 0.f;
#pragma unroll
    for (int d = 32; d >= 1; d >>= 1) e += __shfl_xor(e, d, 64);
    float lse = m + logf(e);
    if (act) out[(size_t)w * 40 + lane] = v - lse;
}

extern "C" void kernel_launch(void* const* d_in, const int* in_sizes, int n_in,
                              void* d_out, int out_size, void* d_ws, size_t ws_size,
                              hipStream_t stream) {
    const float* x   = (const float*)d_in[0];
    const int*   ei  = (const int*)d_in[1];
    const float* Wl1 = (const float*)d_in[2];
    const float* b1  = (const float*)d_in[3];
    const float* Wr1 = (const float*)d_in[4];
    const float* Wl2 = (const float*)d_in[5];
    const float* b2  = (const float*)d_in[6];
    const float* Wr2 = (const float*)d_in[7];
    float* out = (float*)d_out;

    char* ws = (char*)d_ws;
    size_t off = 0;
    auto alloc = [&](size_t bytes) -> void* {
        void* p = ws + off;
        off = (off + bytes + 255) & ~(size_t)255;
        return p;
    };
    int*      degi     = (int*)alloc((size_t)NN * 4);
    int*      offsets  = (int*)alloc((size_t)(NN + 1) * 4);
    int*      cursor   = (int*)alloc((size_t)NN * 4);
    int*      partials = (int*)alloc((size_t)NBLK_SCAN * 4);
    int*      ssrc     = (int*)alloc((size_t)NE * 4);
    ushort_t* W1T      = (ushort_t*)alloc((size_t)256 * 128 * 2);
    ushort_t* W2T      = (ushort_t*)alloc((size_t)128 * 128 * 2);
    ushort_t* xb       = (ushort_t*)alloc((size_t)NN * 128 * 2);
    ushort_t* G1       = (ushort_t*)alloc((size_t)NN * 128 * 2);
    float*    C1root   = (float*)alloc((size_t)NN * 128 * 4);
    ushort_t* s1b      = (ushort_t*)alloc((size_t)NN * 128 * 2);
    ushort_t* G2       = (ushort_t*)alloc((size_t)NN * 40 * 2);
    float*    C2root   = (float*)alloc((size_t)NN * 40 * 4);

    hipMemsetAsync(degi, 0, (size_t)NN * 4, stream);

    pack_weights<<<192, 256, 0, stream>>>(Wl1, Wr1, Wl2, Wr2, W1T, W2T);
    cast_x<<<(NN * 32 + 255) / 256, 256, 0, stream>>>(x, xb);
    deg_hist<<<(NE + 255) / 256, 256, 0, stream>>>(ei, degi);
    scan_partials<<<NBLK_SCAN, 256, 0, stream>>>(degi, partials);
    scan_level2<<<1, 256, 0, stream>>>(partials, offsets);
    scan_finalize<<<NBLK_SCAN, 256, 0, stream>>>(degi, partials, offsets, cursor);
    fill_kernel<<<(NE + 255) / 256, 256, 0, stream>>>(ei, cursor, ssrc);

    dim3 g1((NN + 127) / 128, 2);
    gemm_mfma<<<g1, 256, 0, stream>>>(xb, W1T, G1, C1root, NN, 128, 256);

    aggregate1<<<(NN * 64 + 255) / 256, 256, 0, stream>>>(offsets, ssrc, G1, C1root, b1, s1b);

    dim3 g2((NN + 127) / 128, 1);
    gemm_mfma<<<g2, 256, 0, stream>>>(s1b, W2T, G2, C2root, NN, 40, 80);

    aggregate2<<<(NN * 64 + 255) / 256, 256, 0, stream>>>(offsets, ssrc, G2, C2root, b2, out);
}

// Round 5
// 526.992 us; speedup vs baseline: 7.6838x; 1.0467x over previous
//
#include <hip/hip_runtime.h>
#include <math.h>

#define NN 100000
#define NE 1600000
#define SCAN_CHUNK 512
#define NBLK_SCAN ((NN + SCAN_CHUNK - 1) / SCAN_CHUNK)  // 196
#define NPART 8
#define PSZ ((NN + NPART - 1) / NPART)   // 12500
#define FILL_CHUNKS 128                  // NE/128 = 12500 edges per chunk

typedef __attribute__((ext_vector_type(8))) short short8;
typedef __attribute__((ext_vector_type(4))) float f32x4;
typedef unsigned short ushort_t;
typedef unsigned int uint_t;

__device__ inline ushort_t f2bf(float f) {  // RNE
    uint_t u = __builtin_bit_cast(uint_t, f);
    u += 0x7FFFu + ((u >> 16) & 1u);
    return (ushort_t)(u >> 16);
}
__device__ inline float bf2f(ushort_t b) {
    uint_t u = (uint_t)b << 16;
    return __builtin_bit_cast(float, u);
}
__device__ inline float bits2f(uint_t u) { return __builtin_bit_cast(float, u); }

// ---------------- pack weights (bf16, pre-transposed [N][K])
__global__ void pack_weights(const float* __restrict__ Wl1, const float* __restrict__ Wr1,
                             const float* __restrict__ Wl2, const float* __restrict__ Wr2,
                             ushort_t* __restrict__ W1T, ushort_t* __restrict__ W2T) {
    int gid = blockIdx.x * blockDim.x + threadIdx.x;
    if (gid < 256 * 128) {
        int n = gid >> 7, k = gid & 127;
        float v = (n < 128) ? Wl1[k * 128 + n] : Wr1[k * 128 + (n - 128)];
        W1T[gid] = f2bf(v);
    } else {
        int g = gid - 256 * 128;
        if (g < 128 * 128) {
            int n = g >> 7, k = g & 127;
            float v = 0.0f;
            if (n < 40)      v = Wl2[k * 40 + n];
            else if (n < 80) v = Wr2[k * 40 + (n - 40)];
            W2T[g] = f2bf(v);
        }
    }
}

// ---------------- cast x -> bf16 (4 elems/thread)
__global__ void cast_x(const float* __restrict__ x, ushort_t* __restrict__ xb) {
    int g = blockIdx.x * 256 + threadIdx.x;
    if (g >= NN * 32) return;
    float4 v = ((const float4*)x)[g];
    ushort4 o;
    o.x = f2bf(v.x); o.y = f2bf(v.y); o.z = f2bf(v.z); o.w = f2bf(v.w);
    ((ushort4*)xb)[g] = o;
}

// ---------------- XCD-partitioned degree histogram: partition = blockIdx&7
__global__ __launch_bounds__(256) void deg_hist_part(const int* __restrict__ ei,
                                                     int* __restrict__ degi) {
    int part = blockIdx.x & (NPART - 1);
    int chunk = blockIdx.x >> 3;
    int lo = part * PSZ, hi = lo + PSZ;
    int e0 = chunk * (NE / FILL_CHUNKS);
    int e1 = e0 + (NE / FILL_CHUNKS);
    for (int e = e0 + threadIdx.x; e < e1; e += 256) {
        int dst = ei[NE + e];
        if (dst >= lo && dst < hi) atomicAdd(&degi[dst], 1);
    }
}

// ---------------- scan phase 1: per-block chunk sums
__global__ __launch_bounds__(256) void scan_partials(const int* __restrict__ degi,
                                                     int* __restrict__ partials) {
    __shared__ int lds[4];
    int b = blockIdx.x, t = threadIdx.x;
    int i0 = b * SCAN_CHUNK + t * 2;
    int s = 0;
    if (i0 < NN) s += degi[i0];
    if (i0 + 1 < NN) s += degi[i0 + 1];
#pragma unroll
    for (int d = 32; d >= 1; d >>= 1) s += __shfl_xor(s, d, 64);
    if ((t & 63) == 0) lds[t >> 6] = s;
    __syncthreads();
    if (t == 0) partials[b] = lds[0] + lds[1] + lds[2] + lds[3];
}

// ---------------- scan phase 2: single block scans the partials
__global__ __launch_bounds__(256) void scan_level2(int* __restrict__ partials,
                                                   int* __restrict__ offsets) {
    __shared__ int part[256];
    int t = threadIdx.x;
    int v = (t < NBLK_SCAN) ? partials[t] : 0;
    part[t] = v;
    __syncthreads();
    for (int d = 1; d < 256; d <<= 1) {
        int tmp = (t >= d) ? part[t - d] : 0;
        __syncthreads();
        part[t] += tmp;
        __syncthreads();
    }
    if (t < NBLK_SCAN) partials[t] = part[t] - v;
    if (t == 255) offsets[NN] = part[255];
}

// ---------------- scan phase 3: block-local exclusive scan + base
__global__ __launch_bounds__(256) void scan_finalize(const int* __restrict__ degi,
                                                     const int* __restrict__ partials,
                                                     int* __restrict__ offsets,
                                                     int* __restrict__ cursor) {
    __shared__ int part[256];
    int b = blockIdx.x, t = threadIdx.x;
    int i0 = b * SCAN_CHUNK + t * 2;
    int d0 = (i0 < NN) ? degi[i0] : 0;
    int d1 = (i0 + 1 < NN) ? degi[i0 + 1] : 0;
    int ps = d0 + d1;
    part[t] = ps;
    __syncthreads();
    for (int d = 1; d < 256; d <<= 1) {
        int tmp = (t >= d) ? part[t - d] : 0;
        __syncthreads();
        part[t] += tmp;
        __syncthreads();
    }
    int excl = part[t] - ps + partials[b];
    if (i0 < NN)     { offsets[i0] = excl;          cursor[i0] = excl; }
    if (i0 + 1 < NN) { offsets[i0 + 1] = excl + d0; cursor[i0 + 1] = excl + d0; }
}

// ---------------- XCD-partitioned counting-sort fill
// Each partition owns an exclusive dst range -> exclusive ssrc/cursor region,
// so dirty lines live in one XCD's L2 only (no cross-XCD line stealing).
__global__ __launch_bounds__(256) void fill_part(const int* __restrict__ ei,
                                                 int* __restrict__ cursor,
                                                 int* __restrict__ sorted_src) {
    int part = blockIdx.x & (NPART - 1);
    int chunk = blockIdx.x >> 3;
    int lo = part * PSZ, hi = lo + PSZ;
    int e0 = chunk * (NE / FILL_CHUNKS);
    int e1 = e0 + (NE / FILL_CHUNKS);
    for (int e = e0 + threadIdx.x; e < e1; e += 256) {
        int dst = ei[NE + e];
        if (dst >= lo && dst < hi) {
            int pos = atomicAdd(&cursor[dst], 1);
            sorted_src[pos] = ei[e];
        }
    }
}

// ---------------- bf16 MFMA GEMM: [M,128]bf16 @ Bt^T (Bt is [N][128]bf16)
// cols [0,split) -> G (bf16), cols [split,rootEnd) -> Croot (fp32)
__global__ __launch_bounds__(256) void gemm_mfma(const ushort_t* __restrict__ A,
                                                 const ushort_t* __restrict__ Bt,
                                                 ushort_t* __restrict__ G,
                                                 float* __restrict__ Croot,
                                                 int M, int split, int rootEnd) {
    __shared__ __align__(16) ushort_t As[128 * 72];
    __shared__ __align__(16) ushort_t Bs[128 * 72];
    int tid = threadIdx.x;
    int lane = tid & 63, wid = tid >> 6;
    int quad = lane >> 4, l15 = lane & 15;
    int wm = (wid & 1) * 64, wn = (wid >> 1) * 64;
    int mBase = blockIdx.x * 128, nBase = blockIdx.y * 128;
    int rootW = rootEnd - split;

    f32x4 acc[4][4];
#pragma unroll
    for (int i = 0; i < 4; ++i)
#pragma unroll
        for (int j = 0; j < 4; ++j) acc[i][j] = (f32x4){0.f, 0.f, 0.f, 0.f};

    int lrow = tid >> 1;
    int lcol = (tid & 1) * 32;
    int arow = mBase + lrow;
    const ushort_t* aSrc = A + (size_t)arow * 128 + lcol;
    const ushort_t* bSrc = Bt + (size_t)(nBase + lrow) * 128 + lcol;
    ushort_t* aDst = &As[lrow * 72 + lcol];
    ushort_t* bDst = &Bs[lrow * 72 + lcol];

    for (int kc = 0; kc < 128; kc += 64) {
#pragma unroll
        for (int ii = 0; ii < 4; ++ii) {
            uint4 av = make_uint4(0, 0, 0, 0);
            if (arow < M) av = *(const uint4*)(aSrc + kc + ii * 8);
            *(uint4*)(aDst + ii * 8) = av;
            uint4 bv = *(const uint4*)(bSrc + kc + ii * 8);
            *(uint4*)(bDst + ii * 8) = bv;
        }
        __syncthreads();
#pragma unroll
        for (int kk = 0; kk < 2; ++kk) {
            short8 af[4], bf[4];
#pragma unroll
            for (int i = 0; i < 4; ++i)
                af[i] = *(const short8*)&As[(wm + i * 16 + l15) * 72 + kk * 32 + quad * 8];
#pragma unroll
            for (int j = 0; j < 4; ++j)
                bf[j] = *(const short8*)&Bs[(wn + j * 16 + l15) * 72 + kk * 32 + quad * 8];
#pragma unroll
            for (int i = 0; i < 4; ++i)
#pragma unroll
                for (int j = 0; j < 4; ++j)
                    acc[i][j] = __builtin_amdgcn_mfma_f32_16x16x32_bf16(af[i], bf[j],
                                                                        acc[i][j], 0, 0, 0);
        }
        __syncthreads();
    }
#pragma unroll
    for (int i = 0; i < 4; ++i) {
#pragma unroll
        for (int r = 0; r < 4; ++r) {
            int m = mBase + wm + i * 16 + quad * 4 + r;
            if (m >= M) continue;
#pragma unroll
            for (int j = 0; j < 4; ++j) {
                int n = nBase + wn + j * 16 + l15;
                float v = acc[i][j][r];
                if (n < split) G[(size_t)m * split + n] = f2bf(v);
                else if (n < rootEnd) Croot[(size_t)m * rootW + (n - split)] = v;
            }
        }
    }
}

// ---------------- aggregate layer 1: one wave/node, lane owns ch [2l,2l+1]
__global__ __launch_bounds__(256) void aggregate1(const int* __restrict__ offsets,
                                                  const int* __restrict__ ssrc,
                                                  const ushort_t* __restrict__ G1,
                                                  const float* __restrict__ C1root,
                                                  const float* __restrict__ b1,
                                                  ushort_t* __restrict__ s1b) {
    int w = (blockIdx.x * blockDim.x + threadIdx.x) >> 6;
    int lane = threadIdx.x & 63;
    if (w >= NN) return;
    int start = offsets[w], end = offsets[w + 1];
    const uint_t* G = (const uint_t*)G1;
    float a0 = 0.f, a1 = 0.f, c0 = 0.f, c1 = 0.f;
    int i = start;
    for (; i + 1 < end; i += 2) {
        int s0 = ssrc[i], s1v = ssrc[i + 1];
        uint_t u0 = G[(size_t)s0 * 64 + lane];
        uint_t u1 = G[(size_t)s1v * 64 + lane];
        a0 += bits2f(u0 << 16); a1 += bits2f(u0 & 0xFFFF0000u);
        c0 += bits2f(u1 << 16); c1 += bits2f(u1 & 0xFFFF0000u);
    }
    if (i < end) {
        uint_t u0 = G[(size_t)ssrc[i] * 64 + lane];
        a0 += bits2f(u0 << 16); a1 += bits2f(u0 & 0xFFFF0000u);
    }
    float inv = 1.0f / fmaxf((float)(end - start), 1.0f);
    float2 r = *(const float2*)(C1root + (size_t)w * 128 + lane * 2);
    float2 bb = *(const float2*)(b1 + lane * 2);
    float h0 = fmaxf((a0 + c0) * inv + bb.x + r.x, 0.f);
    float h1 = fmaxf((a1 + c1) * inv + bb.y + r.y, 0.f);
    uint_t o = ((uint_t)f2bf(h1) << 16) | (uint_t)f2bf(h0);
    ((uint_t*)s1b)[(size_t)w * 64 + lane] = o;
}

// ---------------- aggregate layer 2 + log_softmax: one wave/node, lanes 0..39
__global__ __launch_bounds__(256) void aggregate2(const int* __restrict__ offsets,
                                                  const int* __restrict__ ssrc,
                                                  const ushort_t* __restrict__ G2,
                                                  const float* __restrict__ C2root,
                                                  const float* __restrict__ b2,
                                                  float* __restrict__ out) {
    int w = (blockIdx.x * blockDim.x + threadIdx.x) >> 6;
    int lane = threadIdx.x & 63;
    if (w >= NN) return;
    int start = offsets[w], end = offsets[w + 1];
    bool act = lane < 40;
    float acc = 0.f;
    int i = start;
    for (; i + 1 < end; i += 2) {
        int s0 = ssrc[i], s1v = ssrc[i + 1];
        if (act) {
            acc += bf2f(G2[(size_t)s0 * 40 + lane]);
            acc += bf2f(G2[(size_t)s1v * 40 + lane]);
        }
    }
    if (i < end && act) acc += bf2f(G2[(size_t)ssrc[i] * 40 + lane]);
    float inv = 1.0f / fmaxf((float)(end - start), 1.0f);
    float v = -INFINITY;
    if (act) v = acc * inv + b2[lane] + C2root[(size_t)w * 40 + lane];
    float m = v;
#pragma unroll
    for (int d = 32; d >= 1; d >>= 1) m = fmaxf(m, __shfl_xor(m, d, 64));
    float e = act ? expf(v - m) : 0.f;
#pragma unroll
    for (int d = 32; d >= 1; d >>= 1) e += __shfl_xor(e, d, 64);
    float lse = m + logf(e);
    if (act) out[(size_t)w * 40 + lane] = v - lse;
}

extern "C" void kernel_launch(void* const* d_in, const int* in_sizes, int n_in,
                              void* d_out, int out_size, void* d_ws, size_t ws_size,
                              hipStream_t stream) {
    const float* x   = (const float*)d_in[0];
    const int*   ei  = (const int*)d_in[1];
    const float* Wl1 = (const float*)d_in[2];
    const float* b1  = (const float*)d_in[3];
    const float* Wr1 = (const float*)d_in[4];
    const float* Wl2 = (const float*)d_in[5];
    const float* b2  = (const float*)d_in[6];
    const float* Wr2 = (const float*)d_in[7];
    float* out = (float*)d_out;

    char* ws = (char*)d_ws;
    size_t off = 0;
    auto alloc = [&](size_t bytes) -> void* {
        void* p = ws + off;
        off = (off + bytes + 255) & ~(size_t)255;
        return p;
    };
    int*      degi     = (int*)alloc((size_t)NN * 4);
    int*      offsets  = (int*)alloc((size_t)(NN + 1) * 4);
    int*      cursor   = (int*)alloc((size_t)NN * 4);
    int*      partials = (int*)alloc((size_t)NBLK_SCAN * 4);
    int*      ssrc     = (int*)alloc((size_t)NE * 4);
    ushort_t* W1T      = (ushort_t*)alloc((size_t)256 * 128 * 2);
    ushort_t* W2T      = (ushort_t*)alloc((size_t)128 * 128 * 2);
    ushort_t* xb       = (ushort_t*)alloc((size_t)NN * 128 * 2);
    ushort_t* G1       = (ushort_t*)alloc((size_t)NN * 128 * 2);
    float*    C1root   = (float*)alloc((size_t)NN * 128 * 4);
    ushort_t* s1b      = (ushort_t*)alloc((size_t)NN * 128 * 2);
    ushort_t* G2       = (ushort_t*)alloc((size_t)NN * 40 * 2);
    float*    C2root   = (float*)alloc((size_t)NN * 40 * 4);

    hipMemsetAsync(degi, 0, (size_t)NN * 4, stream);

    pack_weights<<<192, 256, 0, stream>>>(Wl1, Wr1, Wl2, Wr2, W1T, W2T);
    cast_x<<<(NN * 32 + 255) / 256, 256, 0, stream>>>(x, xb);
    deg_hist_part<<<FILL_CHUNKS * NPART, 256, 0, stream>>>(ei, degi);
    scan_partials<<<NBLK_SCAN, 256, 0, stream>>>(degi, partials);
    scan_level2<<<1, 256, 0, stream>>>(partials, offsets);
    scan_finalize<<<NBLK_SCAN, 256, 0, stream>>>(degi, partials, offsets, cursor);
    fill_part<<<FILL_CHUNKS * NPART, 256, 0, stream>>>(ei, cursor, ssrc);

    dim3 g1((NN + 127) / 128, 2);
    gemm_mfma<<<g1, 256, 0, stream>>>(xb, W1T, G1, C1root, NN, 128, 256);

    aggregate1<<<(NN * 64 + 255) / 256, 256, 0, stream>>>(offsets, ssrc, G1, C1root, b1, s1b);

    dim3 g2((NN + 127) / 128, 1);
    gemm_mfma<<<g2, 256, 0, stream>>>(s1b, W2T, G2, C2root, NN, 40, 80);

    aggregate2<<<(NN * 64 + 255) / 256, 256, 0, stream>>>(offsets, ssrc, G2, C2root, b2, out);
}

// Round 6
// 461.784 us; speedup vs baseline: 8.7688x; 1.1412x over previous
//
#include <hip/hip_runtime.h>
#include <math.h>

#define NN 100000
#define NE 1600000
#define SCAN_CHUNK 512
#define NBLK_SCAN ((NN + SCAN_CHUNK - 1) / SCAN_CHUNK)  // 196
#define NPART 8
#define PSZ ((NN + NPART - 1) / NPART)   // 12500
#define FILL_CHUNKS 128                  // NE/128 = 12500 edges per chunk

typedef __attribute__((ext_vector_type(8))) short short8;
typedef __attribute__((ext_vector_type(4))) float f32x4;
typedef unsigned short ushort_t;
typedef unsigned int uint_t;

__device__ inline ushort_t f2bf(float f) {  // RNE
    uint_t u = __builtin_bit_cast(uint_t, f);
    u += 0x7FFFu + ((u >> 16) & 1u);
    return (ushort_t)(u >> 16);
}
__device__ inline float bf2f(ushort_t b) {
    uint_t u = (uint_t)b << 16;
    return __builtin_bit_cast(float, u);
}
__device__ inline float bits2f(uint_t u) { return __builtin_bit_cast(float, u); }
__device__ inline float lo16(uint_t u) { return bits2f(u << 16); }
__device__ inline float hi16(uint_t u) { return bits2f(u & 0xFFFF0000u); }

// ---------------- pack weights (bf16, pre-transposed [N][K])
__global__ void pack_weights(const float* __restrict__ Wl1, const float* __restrict__ Wr1,
                             const float* __restrict__ Wl2, const float* __restrict__ Wr2,
                             ushort_t* __restrict__ W1T, ushort_t* __restrict__ W2T) {
    int gid = blockIdx.x * blockDim.x + threadIdx.x;
    if (gid < 256 * 128) {
        int n = gid >> 7, k = gid & 127;
        float v = (n < 128) ? Wl1[k * 128 + n] : Wr1[k * 128 + (n - 128)];
        W1T[gid] = f2bf(v);
    } else {
        int g = gid - 256 * 128;
        if (g < 128 * 128) {
            int n = g >> 7, k = g & 127;
            float v = 0.0f;
            if (n < 40)      v = Wl2[k * 40 + n];
            else if (n < 80) v = Wr2[k * 40 + (n - 40)];
            W2T[g] = f2bf(v);
        }
    }
}

// ---------------- cast x -> bf16 (4 elems/thread)
__global__ void cast_x(const float* __restrict__ x, ushort_t* __restrict__ xb) {
    int g = blockIdx.x * 256 + threadIdx.x;
    if (g >= NN * 32) return;
    float4 v = ((const float4*)x)[g];
    ushort4 o;
    o.x = f2bf(v.x); o.y = f2bf(v.y); o.z = f2bf(v.z); o.w = f2bf(v.w);
    ((ushort4*)xb)[g] = o;
}

// ---------------- XCD-partitioned degree histogram: partition = blockIdx&7
__global__ __launch_bounds__(256) void deg_hist_part(const int* __restrict__ ei,
                                                     int* __restrict__ degi) {
    int part = blockIdx.x & (NPART - 1);
    int chunk = blockIdx.x >> 3;
    int lo = part * PSZ, hi = lo + PSZ;
    int e0 = chunk * (NE / FILL_CHUNKS);
    int e1 = e0 + (NE / FILL_CHUNKS);
    for (int e = e0 + threadIdx.x; e < e1; e += 256) {
        int dst = ei[NE + e];
        if (dst >= lo && dst < hi) atomicAdd(&degi[dst], 1);
    }
}

// ---------------- scan phase 1: per-block chunk sums
__global__ __launch_bounds__(256) void scan_partials(const int* __restrict__ degi,
                                                     int* __restrict__ partials) {
    __shared__ int lds[4];
    int b = blockIdx.x, t = threadIdx.x;
    int i0 = b * SCAN_CHUNK + t * 2;
    int s = 0;
    if (i0 < NN) s += degi[i0];
    if (i0 + 1 < NN) s += degi[i0 + 1];
#pragma unroll
    for (int d = 32; d >= 1; d >>= 1) s += __shfl_xor(s, d, 64);
    if ((t & 63) == 0) lds[t >> 6] = s;
    __syncthreads();
    if (t == 0) partials[b] = lds[0] + lds[1] + lds[2] + lds[3];
}

// ---------------- scan phase 2: single block scans the partials
__global__ __launch_bounds__(256) void scan_level2(int* __restrict__ partials,
                                                   int* __restrict__ offsets) {
    __shared__ int part[256];
    int t = threadIdx.x;
    int v = (t < NBLK_SCAN) ? partials[t] : 0;
    part[t] = v;
    __syncthreads();
    for (int d = 1; d < 256; d <<= 1) {
        int tmp = (t >= d) ? part[t - d] : 0;
        __syncthreads();
        part[t] += tmp;
        __syncthreads();
    }
    if (t < NBLK_SCAN) partials[t] = part[t] - v;
    if (t == 255) offsets[NN] = part[255];
}

// ---------------- scan phase 3: block-local exclusive scan + base
__global__ __launch_bounds__(256) void scan_finalize(const int* __restrict__ degi,
                                                     const int* __restrict__ partials,
                                                     int* __restrict__ offsets,
                                                     int* __restrict__ cursor) {
    __shared__ int part[256];
    int b = blockIdx.x, t = threadIdx.x;
    int i0 = b * SCAN_CHUNK + t * 2;
    int d0 = (i0 < NN) ? degi[i0] : 0;
    int d1 = (i0 + 1 < NN) ? degi[i0 + 1] : 0;
    int ps = d0 + d1;
    part[t] = ps;
    __syncthreads();
    for (int d = 1; d < 256; d <<= 1) {
        int tmp = (t >= d) ? part[t - d] : 0;
        __syncthreads();
        part[t] += tmp;
        __syncthreads();
    }
    int excl = part[t] - ps + partials[b];
    if (i0 < NN)     { offsets[i0] = excl;          cursor[i0] = excl; }
    if (i0 + 1 < NN) { offsets[i0 + 1] = excl + d0; cursor[i0 + 1] = excl + d0; }
}

// ---------------- XCD-partitioned counting-sort fill
__global__ __launch_bounds__(256) void fill_part(const int* __restrict__ ei,
                                                 int* __restrict__ cursor,
                                                 int* __restrict__ sorted_src) {
    int part = blockIdx.x & (NPART - 1);
    int chunk = blockIdx.x >> 3;
    int lo = part * PSZ, hi = lo + PSZ;
    int e0 = chunk * (NE / FILL_CHUNKS);
    int e1 = e0 + (NE / FILL_CHUNKS);
    for (int e = e0 + threadIdx.x; e < e1; e += 256) {
        int dst = ei[NE + e];
        if (dst >= lo && dst < hi) {
            int pos = atomicAdd(&cursor[dst], 1);
            sorted_src[pos] = ei[e];
        }
    }
}

// ---------------- bf16 MFMA GEMM: [M,128]bf16 @ Bt^T (Bt is [N][128]bf16)
// cols [0,split) -> G (bf16, row stride gstride), cols [split,rootEnd) -> Croot (fp32)
__global__ __launch_bounds__(256) void gemm_mfma(const ushort_t* __restrict__ A,
                                                 const ushort_t* __restrict__ Bt,
                                                 ushort_t* __restrict__ G,
                                                 float* __restrict__ Croot,
                                                 int M, int split, int rootEnd, int gstride) {
    __shared__ __align__(16) ushort_t As[128 * 72];
    __shared__ __align__(16) ushort_t Bs[128 * 72];
    int tid = threadIdx.x;
    int lane = tid & 63, wid = tid >> 6;
    int quad = lane >> 4, l15 = lane & 15;
    int wm = (wid & 1) * 64, wn = (wid >> 1) * 64;
    int mBase = blockIdx.x * 128, nBase = blockIdx.y * 128;
    int rootW = rootEnd - split;

    f32x4 acc[4][4];
#pragma unroll
    for (int i = 0; i < 4; ++i)
#pragma unroll
        for (int j = 0; j < 4; ++j) acc[i][j] = (f32x4){0.f, 0.f, 0.f, 0.f};

    int lrow = tid >> 1;
    int lcol = (tid & 1) * 32;
    int arow = mBase + lrow;
    const ushort_t* aSrc = A + (size_t)arow * 128 + lcol;
    const ushort_t* bSrc = Bt + (size_t)(nBase + lrow) * 128 + lcol;
    ushort_t* aDst = &As[lrow * 72 + lcol];
    ushort_t* bDst = &Bs[lrow * 72 + lcol];

    for (int kc = 0; kc < 128; kc += 64) {
#pragma unroll
        for (int ii = 0; ii < 4; ++ii) {
            uint4 av = make_uint4(0, 0, 0, 0);
            if (arow < M) av = *(const uint4*)(aSrc + kc + ii * 8);
            *(uint4*)(aDst + ii * 8) = av;
            uint4 bv = *(const uint4*)(bSrc + kc + ii * 8);
            *(uint4*)(bDst + ii * 8) = bv;
        }
        __syncthreads();
#pragma unroll
        for (int kk = 0; kk < 2; ++kk) {
            short8 af[4], bf[4];
#pragma unroll
            for (int i = 0; i < 4; ++i)
                af[i] = *(const short8*)&As[(wm + i * 16 + l15) * 72 + kk * 32 + quad * 8];
#pragma unroll
            for (int j = 0; j < 4; ++j)
                bf[j] = *(const short8*)&Bs[(wn + j * 16 + l15) * 72 + kk * 32 + quad * 8];
#pragma unroll
            for (int i = 0; i < 4; ++i)
#pragma unroll
                for (int j = 0; j < 4; ++j)
                    acc[i][j] = __builtin_amdgcn_mfma_f32_16x16x32_bf16(af[i], bf[j],
                                                                        acc[i][j], 0, 0, 0);
        }
        __syncthreads();
    }
#pragma unroll
    for (int i = 0; i < 4; ++i) {
#pragma unroll
        for (int r = 0; r < 4; ++r) {
            int m = mBase + wm + i * 16 + quad * 4 + r;
            if (m >= M) continue;
#pragma unroll
            for (int j = 0; j < 4; ++j) {
                int n = nBase + wn + j * 16 + l15;
                float v = acc[i][j][r];
                if (n < split) G[(size_t)m * gstride + n] = f2bf(v);
                else if (n < rootEnd) Croot[(size_t)m * rootW + (n - split)] = v;
            }
        }
    }
}

// ---------------- aggregate layer 1: one wave/node, lane owns ch [2l,2l+1]
// index-broadcast + 4-edge unroll for MLP
__global__ __launch_bounds__(256) void aggregate1(const int* __restrict__ offsets,
                                                  const int* __restrict__ ssrc,
                                                  const ushort_t* __restrict__ G1,
                                                  const float* __restrict__ C1root,
                                                  const float* __restrict__ b1,
                                                  ushort_t* __restrict__ s1b) {
    int w = (blockIdx.x * blockDim.x + threadIdx.x) >> 6;
    int lane = threadIdx.x & 63;
    if (w >= NN) return;
    int start = offsets[w], end = offsets[w + 1];
    const uint_t* G = (const uint_t*)G1;
    float a0 = 0.f, a1 = 0.f;
    for (int base = start; base < end; base += 64) {
        int cnt = min(64, end - base);
        int idx = (base + lane < end) ? ssrc[base + lane] : 0;
        int j = 0;
        for (; j + 4 <= cnt; j += 4) {
            int s0 = __shfl(idx, j, 64);
            int s1v = __shfl(idx, j + 1, 64);
            int s2 = __shfl(idx, j + 2, 64);
            int s3 = __shfl(idx, j + 3, 64);
            uint_t u0 = G[(size_t)s0 * 64 + lane];
            uint_t u1 = G[(size_t)s1v * 64 + lane];
            uint_t u2 = G[(size_t)s2 * 64 + lane];
            uint_t u3 = G[(size_t)s3 * 64 + lane];
            a0 += lo16(u0) + lo16(u1) + lo16(u2) + lo16(u3);
            a1 += hi16(u0) + hi16(u1) + hi16(u2) + hi16(u3);
        }
        for (; j < cnt; ++j) {
            int s0 = __shfl(idx, j, 64);
            uint_t u0 = G[(size_t)s0 * 64 + lane];
            a0 += lo16(u0);
            a1 += hi16(u0);
        }
    }
    float inv = 1.0f / fmaxf((float)(end - start), 1.0f);
    float2 r = *(const float2*)(C1root + (size_t)w * 128 + lane * 2);
    float2 bb = *(const float2*)(b1 + lane * 2);
    float h0 = fmaxf(a0 * inv + bb.x + r.x, 0.f);
    float h1 = fmaxf(a1 * inv + bb.y + r.y, 0.f);
    uint_t o = ((uint_t)f2bf(h1) << 16) | (uint_t)f2bf(h0);
    ((uint_t*)s1b)[(size_t)w * 64 + lane] = o;
}

// ---------------- aggregate layer 2 + log_softmax: one wave/node
// G2 rows padded to 64 bf16 (128B aligned). lanes 0..19 own ch [2l,2l+1].
__global__ __launch_bounds__(256) void aggregate2(const int* __restrict__ offsets,
                                                  const int* __restrict__ ssrc,
                                                  const ushort_t* __restrict__ G2,
                                                  const float* __restrict__ C2root,
                                                  const float* __restrict__ b2,
                                                  float* __restrict__ out) {
    int w = (blockIdx.x * blockDim.x + threadIdx.x) >> 6;
    int lane = threadIdx.x & 63;
    if (w >= NN) return;
    int start = offsets[w], end = offsets[w + 1];
    bool act = lane < 20;
    int gl = act ? lane : 0;
    const uint_t* G = (const uint_t*)G2;
    float a0 = 0.f, a1 = 0.f;
    for (int base = start; base < end; base += 64) {
        int cnt = min(64, end - base);
        int idx = (base + lane < end) ? ssrc[base + lane] : 0;
        int j = 0;
        for (; j + 4 <= cnt; j += 4) {
            int s0 = __shfl(idx, j, 64);
            int s1v = __shfl(idx, j + 1, 64);
            int s2 = __shfl(idx, j + 2, 64);
            int s3 = __shfl(idx, j + 3, 64);
            if (act) {
                uint_t u0 = G[(size_t)s0 * 32 + gl];
                uint_t u1 = G[(size_t)s1v * 32 + gl];
                uint_t u2 = G[(size_t)s2 * 32 + gl];
                uint_t u3 = G[(size_t)s3 * 32 + gl];
                a0 += lo16(u0) + lo16(u1) + lo16(u2) + lo16(u3);
                a1 += hi16(u0) + hi16(u1) + hi16(u2) + hi16(u3);
            }
        }
        for (; j < cnt; ++j) {
            int s0 = __shfl(idx, j, 64);
            if (act) {
                uint_t u0 = G[(size_t)s0 * 32 + gl];
                a0 += lo16(u0);
                a1 += hi16(u0);
            }
        }
    }
    float inv = 1.0f / fmaxf((float)(end - start), 1.0f);
    float v0 = -INFINITY, v1 = -INFINITY;
    if (act) {
        float2 r = *(const float2*)(C2root + (size_t)w * 40 + lane * 2);
        float2 bb = *(const float2*)(b2 + lane * 2);
        v0 = a0 * inv + bb.x + r.x;
        v1 = a1 * inv + bb.y + r.y;
    }
    float m = fmaxf(v0, v1);
#pragma unroll
    for (int d = 32; d >= 1; d >>= 1) m = fmaxf(m, __shfl_xor(m, d, 64));
    float e = act ? (expf(v0 - m) + expf(v1 - m)) : 0.f;
#pragma unroll
    for (int d = 32; d >= 1; d >>= 1) e += __shfl_xor(e, d, 64);
    float lse = m + logf(e);
    if (act) {
        float2 o = make_float2(v0 - lse, v1 - lse);
        *(float2*)(out + (size_t)w * 40 + lane * 2) = o;
    }
}

extern "C" void kernel_launch(void* const* d_in, const int* in_sizes, int n_in,
                              void* d_out, int out_size, void* d_ws, size_t ws_size,
                              hipStream_t stream) {
    const float* x   = (const float*)d_in[0];
    const int*   ei  = (const int*)d_in[1];
    const float* Wl1 = (const float*)d_in[2];
    const float* b1  = (const float*)d_in[3];
    const float* Wr1 = (const float*)d_in[4];
    const float* Wl2 = (const float*)d_in[5];
    const float* b2  = (const float*)d_in[6];
    const float* Wr2 = (const float*)d_in[7];
    float* out = (float*)d_out;

    char* ws = (char*)d_ws;
    size_t off = 0;
    auto alloc = [&](size_t bytes) -> void* {
        void* p = ws + off;
        off = (off + bytes + 255) & ~(size_t)255;
        return p;
    };
    int*      degi     = (int*)alloc((size_t)NN * 4);
    int*      offsets  = (int*)alloc((size_t)(NN + 1) * 4);
    int*      cursor   = (int*)alloc((size_t)NN * 4);
    int*      partials = (int*)alloc((size_t)NBLK_SCAN * 4);
    int*      ssrc     = (int*)alloc((size_t)NE * 4);
    ushort_t* W1T      = (ushort_t*)alloc((size_t)256 * 128 * 2);
    ushort_t* W2T      = (ushort_t*)alloc((size_t)128 * 128 * 2);
    ushort_t* xb       = (ushort_t*)alloc((size_t)NN * 128 * 2);
    ushort_t* G1       = (ushort_t*)alloc((size_t)NN * 128 * 2);
    float*    C1root   = (float*)alloc((size_t)NN * 128 * 4);
    ushort_t* s1b      = (ushort_t*)alloc((size_t)NN * 128 * 2);
    ushort_t* G2       = (ushort_t*)alloc((size_t)NN * 64 * 2);   // padded stride 64
    float*    C2root   = (float*)alloc((size_t)NN * 40 * 4);

    hipMemsetAsync(degi, 0, (size_t)NN * 4, stream);

    pack_weights<<<192, 256, 0, stream>>>(Wl1, Wr1, Wl2, Wr2, W1T, W2T);
    cast_x<<<(NN * 32 + 255) / 256, 256, 0, stream>>>(x, xb);
    deg_hist_part<<<FILL_CHUNKS * NPART, 256, 0, stream>>>(ei, degi);
    scan_partials<<<NBLK_SCAN, 256, 0, stream>>>(degi, partials);
    scan_level2<<<1, 256, 0, stream>>>(partials, offsets);
    scan_finalize<<<NBLK_SCAN, 256, 0, stream>>>(degi, partials, offsets, cursor);
    fill_part<<<FILL_CHUNKS * NPART, 256, 0, stream>>>(ei, cursor, ssrc);

    dim3 g1((NN + 127) / 128, 2);
    gemm_mfma<<<g1, 256, 0, stream>>>(xb, W1T, G1, C1root, NN, 128, 256, 128);

    aggregate1<<<(NN * 64 + 255) / 256, 256, 0, stream>>>(offsets, ssrc, G1, C1root, b1, s1b);

    dim3 g2((NN + 127) / 128, 1);
    gemm_mfma<<<g2, 256, 0, stream>>>(s1b, W2T, G2, C2root, NN, 40, 80, 64);

    aggregate2<<<(NN * 64 + 255) / 256, 256, 0, stream>>>(offsets, ssrc, G2, C2root, b2, out);
}